// Round 2
// 2019.316 us; speedup vs baseline: 1.1972x; 1.1972x over previous
//
#include <hip/hip_runtime.h>
#include <math.h>
#include <string.h>

#define PI_D 3.14159265358979323846264338327950288

// ---------------------------------------------------------------------------
// Scattering2D (J=4, L=8, 256x256, B=16) + MLP, all fp32.
// m>=128 resolutions: row-Stockham-FFT-with-transposed-write, 2 passes per FFT,
//   with the s-fold fused into the final forward pass (never materialize u2f).
// m<=64 resolutions: whole image resident in LDS, full chain
//   (fold -> ifft2 -> abs -> fft2 -> phi-fold -> ifft2_16) in ONE kernel.
// ---------------------------------------------------------------------------

enum { IN_COMPLEX = 0, IN_REAL = 1, IN_MULFOLD = 2 };
enum { OUT_COMPLEX = 0, OUT_ABS = 1, OUT_REAL_S = 2, OUT_COMPLEX_FOLD = 3, OUT_FOLD = 4 };

struct RftParams {
  const float2* srcC;
  const float*  srcR;
  const float*  filt;
  float2* dstC;
  float*  dstR;
  float2* foldDst;       // 16x16 folded spectra accumulator (atomicAdd)
  const float* foldPhi;  // phi at resolution M
  float foldScale;
  int m1;        // source resolution for MULFOLD
  int srcDiv;    // source image = img / srcDiv
  int filtMod;   // filter index = img % filtMod
  float scale;   // ifft scale, applied at load
  float sign;    // -1 forward, +1 inverse
  int chDiv, chBase, b0;   // S-write addressing
  int inMode, outMode;
};

template<int M>
__global__ __launch_bounds__(256) void rft_kernel(RftParams p) {
  constexpr int R = (M >= 64) ? 8 : ((M == 32) ? 16 : 32);   // rows per block
  constexpr int T = (M == 16) ? 4 : ((M == 32) ? 5 : ((M == 64) ? 6 : ((M == 128) ? 7 : 8)));
  __shared__ float2 Abuf[R][M + 1];
  __shared__ float2 Bbuf[R][M + 1];
  __shared__ float2 W[M / 2];
  __shared__ float red[256][2];
  const int tid = threadIdx.x;
  const long rows0 = (long)blockIdx.x * R;

  // twiddle table: W[q] = exp(sign * 2*pi*i * q / M)
  {
    const float base = p.sign * 6.28318530717958647692f / (float)M;
    for (int i = tid; i < M / 2; i += 256) {
      float sv, cv;
      sincosf(base * (float)i, &sv, &cv);
      W[i] = make_float2(cv, sv);
    }
  }

  // ---- load R rows of length M into Abuf ----
  if (p.inMode == IN_COMPLEX) {
    const float2* s = p.srcC + rows0 * M;
    for (int idx = tid; idx < R * M; idx += 256)
      Abuf[idx / M][idx % M] = s[idx];
  } else if (p.inMode == IN_REAL) {
    const float* s = p.srcR + rows0 * M;
    for (int idx = tid; idx < R * M; idx += 256)
      Abuf[idx / M][idx % M] = make_float2(s[idx], 0.f);
  } else {  // IN_MULFOLD: spectrum * filter, folded from m1^2 down to M^2
    const int m1 = p.m1;
    const int k = m1 / M;
    for (int idx = tid; idx < R * M; idx += 256) {
      const int rl = idx / M, c = idx % M;
      const long g = rows0 + rl;
      const long img = g / M;
      const int r = (int)(g - img * M);
      const float2* sp = p.srcC + (img / p.srcDiv) * (long)m1 * m1;
      const float* fp = p.filt + (long)(img % p.filtMod) * m1 * m1;
      float re = 0.f, im = 0.f;
      for (int qr = 0; qr < k; qr++) {
        const long ro = (long)(r + qr * M) * m1;
        const float2* srow = sp + ro;
        const float*  frow = fp + ro;
        for (int qc = 0; qc < k; qc++) {
          const int cc = c + qc * M;
          const float2 v = srow[cc];
          const float fv = frow[cc];
          re = fmaf(v.x, fv, re);
          im = fmaf(v.y, fv, im);
        }
      }
      Abuf[rl][c] = make_float2(re * p.scale, im * p.scale);
    }
  }
  __syncthreads();

  // ---- Stockham radix-2 DIF (autosort), T stages, ping-pong A<->B ----
  #pragma unroll
  for (int t = 0; t < T; t++) {
    const int s = 1 << t;
    float2 (*Src)[M + 1] = (t & 1) ? Bbuf : Abuf;
    float2 (*Dst)[M + 1] = (t & 1) ? Abuf : Bbuf;
    for (int bf = tid; bf < R * (M / 2); bf += 256) {
      const int row = bf / (M / 2);
      const int j = bf - row * (M / 2);
      const float2 a = Src[row][j];
      const float2 b = Src[row][j + M / 2];
      const float2 w = W[j & ~(s - 1)];
      const float vx = a.x - b.x, vy = a.y - b.y;
      const int dc = (j & (s - 1)) + ((j >> t) << (t + 1));
      Dst[row][dc] = make_float2(a.x + b.x, a.y + b.y);
      Dst[row][dc + s] = make_float2(vx * w.x - vy * w.y, vx * w.y + vy * w.x);
    }
    __syncthreads();
  }
  float2 (*P)[M + 1] = (T & 1) ? Bbuf : Abuf;

  // ---- store transposed: out[img][fo][rpos] = FFT(row rpos)[fo] ----
  if (p.outMode == OUT_COMPLEX) {
    for (int idx = tid; idx < R * M; idx += 256) {
      const int rl = idx & (R - 1);
      const int fo = idx / R;
      const long g = rows0 + rl;
      const long img = g / M;
      const int rpos = (int)(g - img * M);
      p.dstC[img * (long)M * M + (long)fo * M + rpos] = P[rl][fo];
    }
  } else if (p.outMode == OUT_ABS) {
    for (int idx = tid; idx < R * M; idx += 256) {
      const int rl = idx & (R - 1);
      const int fo = idx / R;
      const long g = rows0 + rl;
      const long img = g / M;
      const int rpos = (int)(g - img * M);
      const float2 z = P[rl][fo];
      p.dstR[img * (long)M * M + (long)fo * M + rpos] = sqrtf(z.x * z.x + z.y * z.y);
    }
  } else if (p.outMode == OUT_REAL_S) {  // M == 16: scatter Re into S[b][ch][16][16]
    for (int idx = tid; idx < R * M; idx += 256) {
      const int rl = idx & (R - 1);
      const int fo = idx / R;
      const long g = rows0 + rl;
      const long img = g / M;
      const int rpos = (int)(g - img * M);
      const int bidx = (int)(img / p.chDiv) + p.b0;
      const int ch = p.chBase + (int)(img % p.chDiv);
      p.dstR[((long)bidx * 417 + ch) * 256 + fo * M + rpos] = P[rl][fo].x;
    }
  } else if (R == 8) {  // OUT_COMPLEX_FOLD / OUT_FOLD (only used with M>=128, R==8)
    // This block holds complete output rows fo for 8 consecutive columns of the
    // final spectrum. Fold: SF[img][a%16][b%16] += spec[a][b]*phi[a][b]*scale.
    // Thread tid's (rl,fo) set: rl = tid&7 fixed, fo = (tid>>3)+32k -> fo&15 fixed,
    // so each thread accumulates ONE fold entry in registers; threads tid and
    // tid+128 share an entry -> single LDS combine, then 1 global atomicAdd pair.
    const long img0 = rows0 / M;
    const int rbase = (int)(rows0 - img0 * M);
    float ar = 0.f, ai = 0.f;
    for (int idx = tid; idx < R * M; idx += 256) {
      const int rl = idx & 7;
      const int fo = idx >> 3;
      const float2 z = P[rl][fo];
      if (p.outMode == OUT_COMPLEX_FOLD)
        p.dstC[img0 * (long)M * M + (long)fo * M + (rbase + rl)] = z;
      const float ph = p.foldPhi[(long)fo * M + (rbase + rl)] * p.foldScale;
      ar = fmaf(z.x, ph, ar);
      ai = fmaf(z.y, ph, ai);
    }
    red[tid][0] = ar; red[tid][1] = ai;
    __syncthreads();
    if (tid < 128) {
      ar = red[tid][0] + red[tid + 128][0];
      ai = red[tid][1] + red[tid + 128][1];
      const int ro = tid >> 3;
      const int co = (rbase + (tid & 7)) & 15;
      float* fd = (float*)(p.foldDst + img0 * 256 + ro * 16 + co);
      atomicAdd(fd, ar);
      atomicAdd(fd + 1, ai);
    }
  }
}

static void rft_go(int M, int nimg, const RftParams& p, hipStream_t st) {
  const int R = (M >= 64) ? 8 : ((M == 32) ? 16 : 32);
  const int blocks = nimg * M / R;
  switch (M) {
    case 256: rft_kernel<256><<<blocks, 256, 0, st>>>(p); break;
    case 128: rft_kernel<128><<<blocks, 256, 0, st>>>(p); break;
    case  64: rft_kernel< 64><<<blocks, 256, 0, st>>>(p); break;
    case  32: rft_kernel< 32><<<blocks, 256, 0, st>>>(p); break;
    case  16: rft_kernel< 16><<<blocks, 256, 0, st>>>(p); break;
  }
}

// ---------------------------------------------------------------------------
// In-LDS 2D FFT helpers (natural order: rows then columns, no transposes).
// Twiddle tables are built with sign +1; forward FFT negates w.y via sgn.
// ---------------------------------------------------------------------------
template<int N>
__device__ __forceinline__ void stage_rows(float2 (*S_)[N + 1], float2 (*D_)[N + 1],
                                           const float2* W, int t, float sgn) {
  const int tid = threadIdx.x;
  const int s = 1 << t;
  constexpr int half = N / 2;
  for (int bf = tid; bf < N * half; bf += 256) {
    const int row = bf / half;
    const int j = bf - row * half;
    const float2 a = S_[row][j];
    const float2 b = S_[row][j + half];
    const float2 w = W[j & ~(s - 1)];
    const float wy = sgn * w.y;
    const float vx = a.x - b.x, vy = a.y - b.y;
    const int dc = (j & (s - 1)) + ((j >> t) << (t + 1));
    D_[row][dc] = make_float2(a.x + b.x, a.y + b.y);
    D_[row][dc + s] = make_float2(vx * w.x - vy * wy, vx * wy + vy * w.x);
  }
}

template<int N>
__device__ __forceinline__ void stage_cols(float2 (*S_)[N + 1], float2 (*D_)[N + 1],
                                           const float2* W, int t, float sgn) {
  const int tid = threadIdx.x;
  const int s = 1 << t;
  constexpr int half = N / 2;
  for (int bf = tid; bf < N * half; bf += 256) {
    const int col = bf % N;       // consecutive lanes -> consecutive cols (no LDS conflict)
    const int j = bf / N;
    const float2 a = S_[j][col];
    const float2 b = S_[j + half][col];
    const float2 w = W[j & ~(s - 1)];
    const float wy = sgn * w.y;
    const float vx = a.x - b.x, vy = a.y - b.y;
    const int dr = (j & (s - 1)) + ((j >> t) << (t + 1));
    D_[dr][col] = make_float2(a.x + b.x, a.y + b.y);
    D_[dr + s][col] = make_float2(vx * w.x - vy * wy, vx * wy + vy * w.x);
  }
}

// Full 2D FFT on A (ping-pong with B). 2T stages -> result lands back in A.
template<int N>
__device__ __forceinline__ void fft2d(float2 (*A)[N + 1], float2 (*B)[N + 1],
                                      const float2* W, float sgn) {
  constexpr int T = (N == 64) ? 6 : ((N == 32) ? 5 : 4);
  for (int t = 0; t < T; t++) {
    if (t & 1) stage_rows<N>(B, A, W, t, sgn); else stage_rows<N>(A, B, W, t, sgn);
    __syncthreads();
  }
  for (int t = 0; t < T; t++) {
    if ((T + t) & 1) stage_cols<N>(B, A, W, t, sgn); else stage_cols<N>(A, B, W, t, sgn);
    __syncthreads();
  }
}

// ---------------------------------------------------------------------------
// Whole-image chain kernel (MI <= 64): one block per output image.
//   gather-fold(src*psi, MS->MI, 1/MS^2) -> ifft2 -> abs -> fft2
//   [optional write u1f] -> phi-fold (MI->16, 1/MI^2) -> ifft2(16) -> S
// src image = img/8, filter = img%8 (both chain1 (b,l1) and chain2 (b,l1,l2)).
// ---------------------------------------------------------------------------
template<int MS, int MI>
__global__ __launch_bounds__(256) void chain_kernel(const float2* __restrict__ src,
                                                    const float* __restrict__ psi,
                                                    const float* __restrict__ phi,
                                                    float2* __restrict__ u1fOut,
                                                    float* __restrict__ S,
                                                    int chBase, int chDiv) {
  __shared__ float2 A[MI][MI + 1];
  __shared__ float2 B[MI][MI + 1];
  __shared__ float2 FA[16][17];
  __shared__ float2 FB[16][17];
  __shared__ float2 W[MI / 2];
  __shared__ float2 W16[8];
  const int tid = threadIdx.x;
  const int img = blockIdx.x;

  // twiddles, sign +1
  for (int i = tid; i < MI / 2; i += 256) {
    float sv, cv;
    sincosf(6.28318530717958647692f * (float)i / (float)MI, &sv, &cv);
    W[i] = make_float2(cv, sv);
  }
  if (tid < 8) W16[tid] = make_float2(cosf(0.39269908169872415481f * (float)tid),
                                      sinf(0.39269908169872415481f * (float)tid));

  // gather-fold src*psi -> A
  constexpr int K = MS / MI;
  const float sc1 = 1.f / (float)(MS * MS);
  const float2* sp = src + (long)(img >> 3) * MS * MS;
  const float* fp = psi + (long)(img & 7) * MS * MS;
  for (int idx = tid; idx < MI * MI; idx += 256) {
    const int r = idx / MI, c = idx - (idx / MI) * MI;
    float re = 0.f, im = 0.f;
    for (int qr = 0; qr < K; qr++) {
      const long ro = (long)(r + qr * MI) * MS;
      for (int qc = 0; qc < K; qc++) {
        const long pos = ro + (c + qc * MI);
        const float2 v = sp[pos];
        const float fv = fp[pos];
        re = fmaf(v.x, fv, re);
        im = fmaf(v.y, fv, im);
      }
    }
    A[r][c] = make_float2(re * sc1, im * sc1);
  }
  __syncthreads();

  fft2d<MI>(A, B, W, 1.f);      // inverse -> y in A

  for (int idx = tid; idx < MI * MI; idx += 256) {
    const int r = idx / MI, c = idx - (idx / MI) * MI;
    const float2 z = A[r][c];
    A[r][c] = make_float2(sqrtf(z.x * z.x + z.y * z.y), 0.f);
  }
  __syncthreads();

  fft2d<MI>(A, B, W, -1.f);     // forward -> spectrum of u in A

  if (u1fOut) {
    for (int idx = tid; idx < MI * MI; idx += 256) {
      const int r = idx / MI, c = idx - (idx / MI) * MI;
      u1fOut[(long)img * MI * MI + idx] = A[r][c];
    }
  }

  // phi-fold MI -> 16 (256 threads = 256 output coords)
  {
    constexpr int K2 = MI / 16;
    const float sc2 = 1.f / (float)(MI * MI);
    const int ro = tid >> 4, co = tid & 15;
    float re = 0.f, im = 0.f;
    for (int qr = 0; qr < K2; qr++) {
      const int a_ = ro + qr * 16;
      for (int qc = 0; qc < K2; qc++) {
        const int b_ = co + qc * 16;
        const float2 v = A[a_][b_];
        const float fv = phi[a_ * MI + b_];
        re = fmaf(v.x, fv, re);
        im = fmaf(v.y, fv, im);
      }
    }
    FA[ro][co] = make_float2(re * sc2, im * sc2);
  }
  __syncthreads();

  fft2d<16>(FA, FB, W16, 1.f);  // inverse 16x16, unnormalized (scale already applied)

  const long bidx = img / chDiv;
  const int ch = chBase + (img % chDiv);
  S[((long)bidx * 417 + ch) * 256 + tid] = FA[tid >> 4][tid & 15].x;
}

// Final 16x16 inverse FFT of a folded spectrum (from the fused folds), write S.
__global__ __launch_bounds__(256) void ifft16_kernel(const float2* __restrict__ spec,
                                                     float* __restrict__ S,
                                                     int chBase, int chDiv) {
  __shared__ float2 FA[16][17];
  __shared__ float2 FB[16][17];
  __shared__ float2 W16[8];
  const int tid = threadIdx.x;
  const int img = blockIdx.x;
  if (tid < 8) W16[tid] = make_float2(cosf(0.39269908169872415481f * (float)tid),
                                      sinf(0.39269908169872415481f * (float)tid));
  FA[tid >> 4][tid & 15] = spec[(long)img * 256 + tid];
  __syncthreads();
  fft2d<16>(FA, FB, W16, 1.f);
  const long bidx = img / chDiv;
  const int ch = chBase + (img % chDiv);
  S[((long)bidx * 417 + ch) * 256 + tid] = FA[tid >> 4][tid & 15].x;
}

// ---------------------------------------------------------------------------
// Filter banks (computed on device in f64, mirroring numpy exactly)
// PSI banks: (r,js) = (0,0)(0,1)(0,2)(0,3)(1,1)(1,2)(2,1), 8 orientations each
// ---------------------------------------------------------------------------
__device__ const long PSI_CUM[7] = {524288, 1048576, 1572864, 2097152, 2228224, 2359296, 2392064};
__device__ const int  PSI_MM[7]  = {256, 256, 256, 256, 128, 128, 64};
__device__ const int  PSI_JS[7]  = {0, 1, 2, 3, 1, 2, 1};

__device__ __forceinline__ double dfreq(int i, int m) {
  return (double)((i < (m >> 1)) ? i : i - m) / (double)m;
}

__global__ __launch_bounds__(256) void build_psi_kernel(float* psi, int* fmax) {
  const long i = (long)blockIdx.x * 256 + threadIdx.x;
  int bank = 0;
  while (i >= PSI_CUM[bank]) bank++;
  const long base = bank ? PSI_CUM[bank - 1] : 0;
  const long rem = i - base;
  const int m = PSI_MM[bank], js = PSI_JS[bank];
  const long mm2 = (long)m * m;
  const int l = (int)(rem / mm2);
  const long pos = rem - (long)l * mm2;
  const int r = (int)(pos / m), c = (int)(pos - (long)r * m);
  const double sigma = 0.8 * (double)(1 << js);
  const double xi = (3.0 * PI_D / 4.0) / (double)(1 << js);
  const double th = (double)l * PI_D / 8.0;
  const double kx = 2.0 * PI_D * dfreq(r, m);
  const double ky = 2.0 * PI_D * dfreq(c, m);
  const double ct = cos(th), st = sin(th);
  const double w1 = kx * ct + ky * st;
  const double w2 = -kx * st + ky * ct;
  const double s2 = sigma * sigma;
  const double aa  = exp(-0.5 * s2 * ((w1 - xi) * (w1 - xi) + 0.25 * w2 * w2));
  const double env = exp(-0.5 * s2 * (w1 * w1 + 0.25 * w2 * w2));
  const double beta = exp(-0.5 * s2 * xi * xi);
  const double f = aa - beta * env;
  psi[i] = (float)f;

  float v = fmaxf((float)f, 0.f);
  #pragma unroll
  for (int off = 32; off > 0; off >>= 1)
    v = fmaxf(v, __shfl_down(v, off, 64));
  __shared__ float wmax[4];
  const int lane = threadIdx.x & 63, wid = threadIdx.x >> 6;
  if (lane == 0) wmax[wid] = v;
  __syncthreads();
  if (threadIdx.x == 0) {
    const float mv = fmaxf(fmaxf(wmax[0], wmax[1]), fmaxf(wmax[2], wmax[3]));
    atomicMax(&fmax[bank * 8 + l], __float_as_int(mv));
  }
}

__global__ void norm_psi_kernel(float* psi, const int* fmax) {
  const long i = (long)blockIdx.x * 256 + threadIdx.x;
  if (i >= 2392064L) return;
  int bank = 0;
  while (i >= PSI_CUM[bank]) bank++;
  const long base = bank ? PSI_CUM[bank - 1] : 0;
  const long rem = i - base;
  const int m = PSI_MM[bank];
  const int l = (int)(rem / ((long)m * m));
  const float mx = fmaxf(__int_as_float(fmax[bank * 8 + l]), 1e-12f);
  psi[i] = psi[i] / mx;
}

__global__ void build_phi_kernel(float* phi) {
  const long i = (long)blockIdx.x * 256 + threadIdx.x;
  if (i >= 87040L) return;
  int rr; long base;
  if (i < 65536) { rr = 0; base = 0; }
  else if (i < 81920) { rr = 1; base = 65536; }
  else if (i < 86016) { rr = 2; base = 81920; }
  else { rr = 3; base = 86016; }
  const int m = 256 >> rr;
  const double sigma = 0.8 * (double)(1 << (4 - rr));
  const long pos = i - base;
  const int r = (int)(pos / m), c = (int)(pos % m);
  const double kx = 2.0 * PI_D * dfreq(r, m);
  const double ky = 2.0 * PI_D * dfreq(c, m);
  phi[i] = (float)exp(-0.5 * sigma * sigma * (kx * kx + ky * ky));
}

// ---------------------------------------------------------------------------
// MLP
// ---------------------------------------------------------------------------
__global__ __launch_bounds__(256) void mlp1_kernel(const float* __restrict__ S,
                                                   const float* __restrict__ w1,
                                                   float* __restrict__ out1) {
  __shared__ float hs[16][256];
  const int o = blockIdx.x * 256 + threadIdx.x;   // 1024 outputs over 4 blocks
  const int ch = blockIdx.y;                      // 417 k-chunks of 256
  for (int idx = threadIdx.x; idx < 16 * 256; idx += 256) {
    const int b = idx >> 8, kk = idx & 255;
    hs[b][kk] = S[((long)b * 417 + ch) * 256 + kk];
  }
  __syncthreads();
  float acc[16];
  #pragma unroll
  for (int b = 0; b < 16; b++) acc[b] = 0.f;
  const float* wp = w1 + (long)ch * 256 * 1024 + o;
  for (int kk = 0; kk < 256; kk++) {
    const float w = wp[(long)kk * 1024];
    #pragma unroll
    for (int b = 0; b < 16; b++) acc[b] = fmaf(hs[b][kk], w, acc[b]);
  }
  #pragma unroll
  for (int b = 0; b < 16; b++) atomicAdd(&out1[b * 1024 + o], acc[b]);
}

__global__ void l1post_kernel(const float* out1, const float* b1, const float* g,
                              const float* bb, const float* mm, const float* vv, float* h1) {
  const int i = blockIdx.x * 256 + threadIdx.x;
  if (i < 16384) {
    const int o = i & 1023;
    const float xv = fmaxf(out1[i] + b1[o], 0.f);
    const float rs = (float)(1.0 / sqrt((double)vv[o] + 1e-5));
    h1[i] = (xv - mm[o]) * rs * g[o] + bb[o];
  }
}

__global__ __launch_bounds__(256) void mlp2_kernel(const float* h1, const float* w2, const float* b2,
                                                   const float* g, const float* bb, const float* mm,
                                                   const float* vv, float* h2) {
  __shared__ float hs[16][256];
  const int o = blockIdx.x * 256 + threadIdx.x;   // 512 outputs over 2 blocks
  float acc[16];
  #pragma unroll
  for (int b = 0; b < 16; b++) acc[b] = 0.f;
  for (int kc = 0; kc < 4; kc++) {
    __syncthreads();
    for (int idx = threadIdx.x; idx < 16 * 256; idx += 256) {
      const int b = idx >> 8, kk = idx & 255;
      hs[b][kk] = h1[b * 1024 + kc * 256 + kk];
    }
    __syncthreads();
    for (int kk = 0; kk < 256; kk++) {
      const float w = w2[(long)(kc * 256 + kk) * 512 + o];
      #pragma unroll
      for (int b = 0; b < 16; b++) acc[b] = fmaf(hs[b][kk], w, acc[b]);
    }
  }
  const float bias = b2[o], gg = g[o], bbv = bb[o], mv = mm[o];
  const float rs = (float)(1.0 / sqrt((double)vv[o] + 1e-5));
  for (int b = 0; b < 16; b++) {
    const float xv = fmaxf(acc[b] + bias, 0.f);
    h2[b * 512 + o] = (xv - mv) * rs * gg + bbv;
  }
}

__global__ __launch_bounds__(128) void mlp3_kernel(const float* h2, const float* w3, const float* b3,
                                                   const float* g, const float* bb, const float* mm,
                                                   const float* vv, float* h3) {
  __shared__ float hs[16][256];
  const int o = threadIdx.x;   // 128 outputs
  float acc[16];
  #pragma unroll
  for (int b = 0; b < 16; b++) acc[b] = 0.f;
  for (int kc = 0; kc < 2; kc++) {
    __syncthreads();
    for (int idx = threadIdx.x; idx < 16 * 256; idx += 128) {
      const int b = idx >> 8, kk = idx & 255;
      hs[b][kk] = h2[b * 512 + kc * 256 + kk];
    }
    __syncthreads();
    for (int kk = 0; kk < 256; kk++) {
      const float w = w3[(kc * 256 + kk) * 128 + o];
      #pragma unroll
      for (int b = 0; b < 16; b++) acc[b] = fmaf(hs[b][kk], w, acc[b]);
    }
  }
  const float bias = b3[o], gg = g[o], bbv = bb[o], mv = mm[o];
  const float rs = (float)(1.0 / sqrt((double)vv[o] + 1e-5));
  for (int b = 0; b < 16; b++) {
    const float xv = fmaxf(acc[b] + bias, 0.f);
    h3[b * 128 + o] = (xv - mv) * rs * gg + bbv;
  }
}

__global__ void mlp4_kernel(const float* h3, const float* w4, const float* b4, float* out) {
  const int b = threadIdx.x;
  if (b < 16) {
    double a = 0.0;
    for (int k = 0; k < 128; k++) a += (double)h3[b * 128 + k] * (double)w4[k];
    out[b] = (float)(a + (double)b4[0]);
  }
}

// ---------------------------------------------------------------------------
// Orchestration
// ---------------------------------------------------------------------------
static RftParams rp0() {
  RftParams p;
  memset(&p, 0, sizeof(p));
  p.srcDiv = 1; p.filtMod = 1; p.chDiv = 1;
  p.scale = 1.f; p.sign = -1.f; p.m1 = 0;
  return p;
}

extern "C" void kernel_launch(void* const* d_in, const int* in_sizes, int n_in,
                              void* d_out, int out_size, void* d_ws, size_t ws_size,
                              hipStream_t stream) {
  (void)in_sizes; (void)n_in; (void)out_size; (void)ws_size;
  const float* x    = (const float*)d_in[0];
  const float* w1   = (const float*)d_in[1];
  const float* b1   = (const float*)d_in[2];
  const float* bn1g = (const float*)d_in[3];
  const float* bn1b = (const float*)d_in[4];
  const float* bn1m = (const float*)d_in[5];
  const float* bn1v = (const float*)d_in[6];
  const float* w2   = (const float*)d_in[7];
  const float* b2   = (const float*)d_in[8];
  const float* bn2g = (const float*)d_in[9];
  const float* bn2b = (const float*)d_in[10];
  const float* bn2m = (const float*)d_in[11];
  const float* bn2v = (const float*)d_in[12];
  const float* w3   = (const float*)d_in[13];
  const float* b3   = (const float*)d_in[14];
  const float* bn3g = (const float*)d_in[15];
  const float* bn3b = (const float*)d_in[16];
  const float* bn3m = (const float*)d_in[17];
  const float* bn3v = (const float*)d_in[18];
  const float* w4   = (const float*)d_in[19];
  const float* b4   = (const float*)d_in[20];

  char* ws = (char*)d_ws;
  float2* XF   = (float2*)(ws + 0);              //   8.0 MiB: fft2(x), 16 x 256^2
  float2* BUF1 = (float2*)(ws + 8388608);        //  64.0 MiB ping (complex)
  float2* BUF2 = (float2*)(ws + 75497472);       //  32.0 MiB (real abs images)
  float2* U1F0 = (float2*)(ws + 109051904);      //  64.0 MiB: u1f at j1=0 (128 x 256^2)
  float2* U1F1 = (float2*)(ws + 176160768);      //  16.0 MiB: u1f at j1=1 (128 x 128^2)
  float2* U1F2 = (float2*)(ws + 192937984);      //   4.0 MiB: u1f at j1=2 (128 x  64^2)
  float*  S    = (float*)(ws + 197132288);       //   6.5 MiB: 16 x 417 x 256
  float*  PSI  = (float*)(ws + 203964416);       //   9.1 MiB
  float*  PHI  = (float*)(ws + 213532672);       //   0.3 MiB
  int*    FMAX = (int*)(ws + 213880832);         //   256 B
  float2* SF   = (float2*)(ws + 213881088);      //   2.5 MiB: folded 16x16 spectra
  float*  OUT1 = (float*)(ws + 216502528);       //  16 x 1024
  float*  H1   = (float*)(ws + 216568064);
  float*  H2   = (float*)(ws + 216633600);
  float*  H3   = (float*)(ws + 216666368);

  float2* SF0  = SF;                 // j1=0 s1 spectra: 128 imgs
  float2* SF1  = SF + 128 * 256;     // j1=1 s1 spectra: 128 imgs
  float2* SF01 = SF + 256 * 256;     // (0,1) s2 spectra: 1024 imgs

  static const int psioff[7] = {0, 524288, 1048576, 1572864, 2097152, 2228224, 2359296};
  static const int phioff[4] = {0, 65536, 81920, 86016};

  // ---- filters (deterministic, rebuilt every call) ----
  hipMemsetAsync(FMAX, 0, 256, stream);
  hipMemsetAsync(SF, 0, 1280 * 256 * sizeof(float2), stream);
  build_psi_kernel<<<9344, 256, 0, stream>>>(PSI, FMAX);
  norm_psi_kernel<<<9344, 256, 0, stream>>>(PSI, FMAX);
  build_phi_kernel<<<340, 256, 0, stream>>>(PHI);

  // ---- Xf = fft2(x) ----
  { RftParams p = rp0(); p.inMode = IN_REAL; p.srcR = x; p.outMode = OUT_COMPLEX; p.dstC = BUF1; p.sign = -1.f; rft_go(256, 16, p, stream); }
  { RftParams p = rp0(); p.inMode = IN_COMPLEX; p.srcC = BUF1; p.outMode = OUT_COMPLEX; p.dstC = XF; p.sign = -1.f; rft_go(256, 16, p, stream); }

  // ---- s0 = Re(ifft16(fold(Xf*phi0))) ----
  { RftParams p = rp0(); p.inMode = IN_MULFOLD; p.srcC = XF; p.filt = PHI + phioff[0]; p.m1 = 256; p.srcDiv = 1; p.filtMod = 1; p.scale = 1.f / 65536.f; p.sign = 1.f; p.outMode = OUT_COMPLEX; p.dstC = BUF1; rft_go(16, 16, p, stream); }
  { RftParams p = rp0(); p.inMode = IN_COMPLEX; p.srcC = BUF1; p.sign = 1.f; p.outMode = OUT_REAL_S; p.dstR = S; p.chDiv = 1; p.chBase = 0; p.b0 = 0; rft_go(16, 16, p, stream); }

  // ---- first order, j1 = 0,1 (m1 = 256,128): 4 rft passes, fold fused in p4 ----
  for (int j1 = 0; j1 < 2; j1++) {
    const int m1 = 256 >> j1;
    const float isc1 = 1.f / (float)(m1 * m1);
    float2* U  = (j1 == 0) ? U1F0 : U1F1;
    float2* SFj = (j1 == 0) ? SF0 : SF1;
    { RftParams p = rp0(); p.inMode = IN_MULFOLD; p.srcC = XF; p.filt = PSI + psioff[j1]; p.m1 = 256; p.srcDiv = 8; p.filtMod = 8; p.scale = 1.f / 65536.f; p.sign = 1.f; p.outMode = OUT_COMPLEX; p.dstC = BUF1; rft_go(m1, 128, p, stream); }
    { RftParams p = rp0(); p.inMode = IN_COMPLEX; p.srcC = BUF1; p.sign = 1.f; p.outMode = OUT_ABS; p.dstR = (float*)BUF2; rft_go(m1, 128, p, stream); }
    { RftParams p = rp0(); p.inMode = IN_REAL; p.srcR = (const float*)BUF2; p.sign = -1.f; p.outMode = OUT_COMPLEX; p.dstC = BUF1; rft_go(m1, 128, p, stream); }
    { RftParams p = rp0(); p.inMode = IN_COMPLEX; p.srcC = BUF1; p.sign = -1.f; p.outMode = OUT_COMPLEX_FOLD; p.dstC = U;
      p.foldDst = SFj; p.foldPhi = PHI + phioff[j1]; p.foldScale = isc1; rft_go(m1, 128, p, stream); }
    ifft16_kernel<<<128, 256, 0, stream>>>(SFj, S, 1 + 8 * j1, 8);
  }

  // ---- first order, j1 = 2,3: whole-image chain kernels ----
  chain_kernel<256, 64><<<128, 256, 0, stream>>>(XF, PSI + psioff[2], PHI + phioff[2], U1F2, S, 17, 8);
  chain_kernel<256, 32><<<128, 256, 0, stream>>>(XF, PSI + psioff[3], PHI + phioff[3], nullptr, S, 25, 8);

  // ---- second order (0,1), m2 = 128: 4 rft passes per chunk, u2f never written ----
  for (int cc = 0; cc < 2; cc++) {
    const int b0 = cc * 8;
    const float2* u1fsrc = U1F0 + (long)b0 * 8 * 65536;
    { RftParams p = rp0(); p.inMode = IN_MULFOLD; p.srcC = u1fsrc; p.filt = PSI + psioff[1]; p.m1 = 256; p.srcDiv = 8; p.filtMod = 8; p.scale = 1.f / 65536.f; p.sign = 1.f; p.outMode = OUT_COMPLEX; p.dstC = BUF1; rft_go(128, 512, p, stream); }
    { RftParams p = rp0(); p.inMode = IN_COMPLEX; p.srcC = BUF1; p.sign = 1.f; p.outMode = OUT_ABS; p.dstR = (float*)BUF2; rft_go(128, 512, p, stream); }
    { RftParams p = rp0(); p.inMode = IN_REAL; p.srcR = (const float*)BUF2; p.sign = -1.f; p.outMode = OUT_COMPLEX; p.dstC = BUF1; rft_go(128, 512, p, stream); }
    { RftParams p = rp0(); p.inMode = IN_COMPLEX; p.srcC = BUF1; p.sign = -1.f; p.outMode = OUT_FOLD;
      p.foldDst = SF01 + (long)b0 * 64 * 256; p.foldPhi = PHI + phioff[1]; p.foldScale = 1.f / 16384.f; rft_go(128, 512, p, stream); }
  }
  ifft16_kernel<<<1024, 256, 0, stream>>>(SF01, S, 33, 64);

  // ---- second order, m2 <= 64: whole-image chain kernels (no intermediates) ----
  chain_kernel<256, 64><<<1024, 256, 0, stream>>>(U1F0, PSI + psioff[2], PHI + phioff[2], nullptr, S,  97, 64);
  chain_kernel<256, 32><<<1024, 256, 0, stream>>>(U1F0, PSI + psioff[3], PHI + phioff[3], nullptr, S, 161, 64);
  chain_kernel<128, 64><<<1024, 256, 0, stream>>>(U1F1, PSI + psioff[4], PHI + phioff[2], nullptr, S, 225, 64);
  chain_kernel<128, 32><<<1024, 256, 0, stream>>>(U1F1, PSI + psioff[5], PHI + phioff[3], nullptr, S, 289, 64);
  chain_kernel< 64, 32><<<1024, 256, 0, stream>>>(U1F2, PSI + psioff[6], PHI + phioff[3], nullptr, S, 353, 64);

  // ---- MLP ----
  hipMemsetAsync(OUT1, 0, 16 * 1024 * 4, stream);
  mlp1_kernel<<<dim3(4, 417), 256, 0, stream>>>(S, w1, OUT1);
  l1post_kernel<<<64, 256, 0, stream>>>(OUT1, b1, bn1g, bn1b, bn1m, bn1v, H1);
  mlp2_kernel<<<2, 256, 0, stream>>>(H1, w2, b2, bn2g, bn2b, bn2m, bn2v, H2);
  mlp3_kernel<<<1, 128, 0, stream>>>(H2, w3, b3, bn3g, bn3b, bn3m, bn3v, H3);
  mlp4_kernel<<<1, 64, 0, stream>>>(H3, w4, b4, (float*)d_out);
}

// Round 3
// 1781.541 us; speedup vs baseline: 1.3570x; 1.1335x over previous
//
#include <hip/hip_runtime.h>
#include <math.h>
#include <string.h>

#define PI_D 3.14159265358979323846264338327950288

// ---------------------------------------------------------------------------
// Scattering2D (J=4, L=8, 256x256, B=16) + MLP, all fp32.
// m>=128 resolutions: row-Stockham-FFT-with-transposed-write, 2 passes per FFT,
//   with the s-fold fused into the final forward pass (never materialize u2f).
// m<=64 resolutions: fold8 kernel (reads each source pixel ONCE, applies all
//   8 orientation filters in registers) -> prefolded whole-image LDS chain
//   (ifft2 -> abs -> fft2 -> phi-fold -> ifft2_16) in one kernel.
// ---------------------------------------------------------------------------

enum { IN_COMPLEX = 0, IN_REAL = 1, IN_MULFOLD = 2 };
enum { OUT_COMPLEX = 0, OUT_ABS = 1, OUT_REAL_S = 2, OUT_COMPLEX_FOLD = 3, OUT_FOLD = 4 };

struct RftParams {
  const float2* srcC;
  const float*  srcR;
  const float*  filt;
  float2* dstC;
  float*  dstR;
  float2* foldDst;       // 16x16 folded spectra accumulator (atomicAdd)
  const float* foldPhi;  // phi at resolution M
  float foldScale;
  int m1;        // source resolution for MULFOLD
  int srcDiv;    // source image = img / srcDiv
  int filtMod;   // filter index = img % filtMod
  float scale;   // ifft scale, applied at load
  float sign;    // -1 forward, +1 inverse
  int chDiv, chBase, b0;   // S-write addressing
  int inMode, outMode;
};

template<int M>
__global__ __launch_bounds__(256) void rft_kernel(RftParams p) {
  constexpr int R = 8;   // rows per block (M >= 128 only)
  constexpr int T = (M == 128) ? 7 : 8;
  __shared__ float2 Abuf[R][M + 1];
  __shared__ float2 Bbuf[R][M + 1];
  __shared__ float2 W[M / 2];
  __shared__ float red[256][2];
  const int tid = threadIdx.x;
  const long rows0 = (long)blockIdx.x * R;

  // twiddle table: W[q] = exp(sign * 2*pi*i * q / M)
  {
    const float base = p.sign * 6.28318530717958647692f / (float)M;
    for (int i = tid; i < M / 2; i += 256) {
      float sv, cv;
      sincosf(base * (float)i, &sv, &cv);
      W[i] = make_float2(cv, sv);
    }
  }

  // ---- load R rows of length M into Abuf ----
  if (p.inMode == IN_COMPLEX) {
    const float2* s = p.srcC + rows0 * M;
    for (int idx = tid; idx < R * M; idx += 256)
      Abuf[idx / M][idx % M] = s[idx];
  } else if (p.inMode == IN_REAL) {
    const float* s = p.srcR + rows0 * M;
    for (int idx = tid; idx < R * M; idx += 256)
      Abuf[idx / M][idx % M] = make_float2(s[idx], 0.f);
  } else {  // IN_MULFOLD: spectrum * filter, folded from m1^2 down to M^2
    const int m1 = p.m1;
    const int k = m1 / M;
    for (int idx = tid; idx < R * M; idx += 256) {
      const int rl = idx / M, c = idx % M;
      const long g = rows0 + rl;
      const long img = g / M;
      const int r = (int)(g - img * M);
      const float2* sp = p.srcC + (img / p.srcDiv) * (long)m1 * m1;
      const float* fp = p.filt + (long)(img % p.filtMod) * m1 * m1;
      float re = 0.f, im = 0.f;
      for (int qr = 0; qr < k; qr++) {
        const long ro = (long)(r + qr * M) * m1;
        const float2* srow = sp + ro;
        const float*  frow = fp + ro;
        for (int qc = 0; qc < k; qc++) {
          const int cc = c + qc * M;
          const float2 v = srow[cc];
          const float fv = frow[cc];
          re = fmaf(v.x, fv, re);
          im = fmaf(v.y, fv, im);
        }
      }
      Abuf[rl][c] = make_float2(re * p.scale, im * p.scale);
    }
  }
  __syncthreads();

  // ---- Stockham radix-2 DIF (autosort), T stages, ping-pong A<->B ----
  #pragma unroll
  for (int t = 0; t < T; t++) {
    const int s = 1 << t;
    float2 (*Src)[M + 1] = (t & 1) ? Bbuf : Abuf;
    float2 (*Dst)[M + 1] = (t & 1) ? Abuf : Bbuf;
    for (int bf = tid; bf < R * (M / 2); bf += 256) {
      const int row = bf / (M / 2);
      const int j = bf - row * (M / 2);
      const float2 a = Src[row][j];
      const float2 b = Src[row][j + M / 2];
      const float2 w = W[j & ~(s - 1)];
      const float vx = a.x - b.x, vy = a.y - b.y;
      const int dc = (j & (s - 1)) + ((j >> t) << (t + 1));
      Dst[row][dc] = make_float2(a.x + b.x, a.y + b.y);
      Dst[row][dc + s] = make_float2(vx * w.x - vy * w.y, vx * w.y + vy * w.x);
    }
    __syncthreads();
  }
  float2 (*P)[M + 1] = (T & 1) ? Bbuf : Abuf;

  // ---- store transposed: out[img][fo][rpos] = FFT(row rpos)[fo] ----
  if (p.outMode == OUT_COMPLEX) {
    for (int idx = tid; idx < R * M; idx += 256) {
      const int rl = idx & (R - 1);
      const int fo = idx / R;
      const long g = rows0 + rl;
      const long img = g / M;
      const int rpos = (int)(g - img * M);
      p.dstC[img * (long)M * M + (long)fo * M + rpos] = P[rl][fo];
    }
  } else if (p.outMode == OUT_ABS) {
    for (int idx = tid; idx < R * M; idx += 256) {
      const int rl = idx & (R - 1);
      const int fo = idx / R;
      const long g = rows0 + rl;
      const long img = g / M;
      const int rpos = (int)(g - img * M);
      const float2 z = P[rl][fo];
      p.dstR[img * (long)M * M + (long)fo * M + rpos] = sqrtf(z.x * z.x + z.y * z.y);
    }
  } else {  // OUT_COMPLEX_FOLD / OUT_FOLD (M>=128, R==8)
    // Block holds complete output rows fo for 8 consecutive columns of the
    // final spectrum. Fold: SF[img][a%16][b%16] += spec[a][b]*phi[a][b]*scale.
    // rl = tid&7 fixed, fo%16 fixed per thread -> each thread accumulates ONE
    // fold entry; threads tid and tid+128 share it -> LDS combine + 1 atomic pair.
    const long img0 = rows0 / M;
    const int rbase = (int)(rows0 - img0 * M);
    float ar = 0.f, ai = 0.f;
    for (int idx = tid; idx < R * M; idx += 256) {
      const int rl = idx & 7;
      const int fo = idx >> 3;
      const float2 z = P[rl][fo];
      if (p.outMode == OUT_COMPLEX_FOLD)
        p.dstC[img0 * (long)M * M + (long)fo * M + (rbase + rl)] = z;
      const float ph = p.foldPhi[(long)fo * M + (rbase + rl)] * p.foldScale;
      ar = fmaf(z.x, ph, ar);
      ai = fmaf(z.y, ph, ai);
    }
    red[tid][0] = ar; red[tid][1] = ai;
    __syncthreads();
    if (tid < 128) {
      ar = red[tid][0] + red[tid + 128][0];
      ai = red[tid][1] + red[tid + 128][1];
      const int ro = tid >> 3;
      const int co = (rbase + (tid & 7)) & 15;
      float* fd = (float*)(p.foldDst + img0 * 256 + ro * 16 + co);
      atomicAdd(fd, ar);
      atomicAdd(fd + 1, ai);
    }
  }
}

static void rft_go(int M, int nimg, const RftParams& p, hipStream_t st) {
  const int blocks = nimg * M / 8;
  switch (M) {
    case 256: rft_kernel<256><<<blocks, 256, 0, st>>>(p); break;
    case 128: rft_kernel<128><<<blocks, 256, 0, st>>>(p); break;
  }
}

// ---------------------------------------------------------------------------
// fold8: folded[src*8+l][r][c] = scale * sum_q src[r+qr*M2][c+qc*M2]*filt_l[...]
// Reads each source pixel ONCE, applies all 8 orientation filters in registers.
// Filter bank (8*M1^2 floats) is L2-resident after the first source image.
// ---------------------------------------------------------------------------
template<int M1, int M2>
__global__ __launch_bounds__(256) void fold8_kernel(const float2* __restrict__ src,
                                                    const float* __restrict__ filt,
                                                    float2* __restrict__ out,
                                                    float scale) {
  constexpr int K = M1 / M2;
  constexpr long MM1 = (long)M1 * M1;
  constexpr int MM2 = M2 * M2;
  constexpr int PXB = MM2 / 256;
  const int s = blockIdx.x / PXB;
  const int px = (blockIdx.x % PXB) * 256 + threadIdx.x;
  const int r = px / M2, c = px - (px / M2) * M2;
  const float2* sp = src + (long)s * MM1;
  float ar[8], ai[8];
  #pragma unroll
  for (int l = 0; l < 8; l++) { ar[l] = 0.f; ai[l] = 0.f; }
  for (int qr = 0; qr < K; qr++) {
    const int R_ = r + qr * M2;
    for (int qc = 0; qc < K; qc++) {
      const long pos = (long)R_ * M1 + (c + qc * M2);
      const float2 v = sp[pos];
      #pragma unroll
      for (int l = 0; l < 8; l++) {
        const float f = filt[l * MM1 + pos];
        ar[l] = fmaf(v.x, f, ar[l]);
        ai[l] = fmaf(v.y, f, ai[l]);
      }
    }
  }
  #pragma unroll
  for (int l = 0; l < 8; l++)
    out[((long)s * 8 + l) * MM2 + px] = make_float2(ar[l] * scale, ai[l] * scale);
}

// ---------------------------------------------------------------------------
// In-LDS 2D FFT helpers (natural order: rows then columns, no transposes).
// Twiddle tables are built with sign +1; forward FFT negates w.y via sgn.
// ---------------------------------------------------------------------------
template<int N>
__device__ __forceinline__ void stage_rows(float2 (*S_)[N + 1], float2 (*D_)[N + 1],
                                           const float2* W, int t, float sgn) {
  const int tid = threadIdx.x;
  const int s = 1 << t;
  constexpr int half = N / 2;
  for (int bf = tid; bf < N * half; bf += 256) {
    const int row = bf / half;
    const int j = bf - row * half;
    const float2 a = S_[row][j];
    const float2 b = S_[row][j + half];
    const float2 w = W[j & ~(s - 1)];
    const float wy = sgn * w.y;
    const float vx = a.x - b.x, vy = a.y - b.y;
    const int dc = (j & (s - 1)) + ((j >> t) << (t + 1));
    D_[row][dc] = make_float2(a.x + b.x, a.y + b.y);
    D_[row][dc + s] = make_float2(vx * w.x - vy * wy, vx * wy + vy * w.x);
  }
}

template<int N>
__device__ __forceinline__ void stage_cols(float2 (*S_)[N + 1], float2 (*D_)[N + 1],
                                           const float2* W, int t, float sgn) {
  const int tid = threadIdx.x;
  const int s = 1 << t;
  constexpr int half = N / 2;
  for (int bf = tid; bf < N * half; bf += 256) {
    const int col = bf % N;       // consecutive lanes -> consecutive cols
    const int j = bf / N;
    const float2 a = S_[j][col];
    const float2 b = S_[j + half][col];
    const float2 w = W[j & ~(s - 1)];
    const float wy = sgn * w.y;
    const float vx = a.x - b.x, vy = a.y - b.y;
    const int dr = (j & (s - 1)) + ((j >> t) << (t + 1));
    D_[dr][col] = make_float2(a.x + b.x, a.y + b.y);
    D_[dr + s][col] = make_float2(vx * w.x - vy * wy, vx * wy + vy * w.x);
  }
}

// Full 2D FFT on A (ping-pong with B). 2T stages -> result lands back in A.
template<int N>
__device__ __forceinline__ void fft2d(float2 (*A)[N + 1], float2 (*B)[N + 1],
                                      const float2* W, float sgn) {
  constexpr int T = (N == 64) ? 6 : ((N == 32) ? 5 : 4);
  for (int t = 0; t < T; t++) {
    if (t & 1) stage_rows<N>(B, A, W, t, sgn); else stage_rows<N>(A, B, W, t, sgn);
    __syncthreads();
  }
  for (int t = 0; t < T; t++) {
    if ((T + t) & 1) stage_cols<N>(B, A, W, t, sgn); else stage_cols<N>(A, B, W, t, sgn);
    __syncthreads();
  }
}

// ---------------------------------------------------------------------------
// Whole-image chain kernel (MI <= 64): one block per output image.
//   load (prefolded: psi==nullptr, coalesced; else gather-fold src*psi)
//   -> ifft2 -> abs -> fft2 -> [optional write u1f] -> phi-fold -> ifft2_16 -> S
// ---------------------------------------------------------------------------
template<int MS, int MI>
__global__ __launch_bounds__(256) void chain_kernel(const float2* __restrict__ src,
                                                    const float* __restrict__ psi,
                                                    const float* __restrict__ phi,
                                                    float2* __restrict__ u1fOut,
                                                    float* __restrict__ S,
                                                    int chBase, int chDiv) {
  __shared__ float2 A[MI][MI + 1];
  __shared__ float2 B[MI][MI + 1];
  __shared__ float2 FA[16][17];
  __shared__ float2 FB[16][17];
  __shared__ float2 W[MI / 2];
  __shared__ float2 W16[8];
  const int tid = threadIdx.x;
  const int img = blockIdx.x;

  // twiddles, sign +1
  for (int i = tid; i < MI / 2; i += 256) {
    float sv, cv;
    sincosf(6.28318530717958647692f * (float)i / (float)MI, &sv, &cv);
    W[i] = make_float2(cv, sv);
  }
  if (tid < 8) W16[tid] = make_float2(cosf(0.39269908169872415481f * (float)tid),
                                      sinf(0.39269908169872415481f * (float)tid));

  if (psi == nullptr) {   // prefolded input (already scaled)
    const float2* sp = src + (long)img * MI * MI;
    for (int idx = tid; idx < MI * MI; idx += 256)
      A[idx / MI][idx - (idx / MI) * MI] = sp[idx];
  } else {                // gather-fold src*psi -> A
    constexpr int K = MS / MI;
    const float sc1 = 1.f / (float)(MS * MS);
    const float2* sp = src + (long)(img >> 3) * MS * MS;
    const float* fp = psi + (long)(img & 7) * MS * MS;
    for (int idx = tid; idx < MI * MI; idx += 256) {
      const int r = idx / MI, c = idx - (idx / MI) * MI;
      float re = 0.f, im = 0.f;
      for (int qr = 0; qr < K; qr++) {
        const long ro = (long)(r + qr * MI) * MS;
        for (int qc = 0; qc < K; qc++) {
          const long pos = ro + (c + qc * MI);
          const float2 v = sp[pos];
          const float fv = fp[pos];
          re = fmaf(v.x, fv, re);
          im = fmaf(v.y, fv, im);
        }
      }
      A[r][c] = make_float2(re * sc1, im * sc1);
    }
  }
  __syncthreads();

  fft2d<MI>(A, B, W, 1.f);      // inverse -> y in A

  for (int idx = tid; idx < MI * MI; idx += 256) {
    const int r = idx / MI, c = idx - (idx / MI) * MI;
    const float2 z = A[r][c];
    A[r][c] = make_float2(sqrtf(z.x * z.x + z.y * z.y), 0.f);
  }
  __syncthreads();

  fft2d<MI>(A, B, W, -1.f);     // forward -> spectrum of u in A

  if (u1fOut) {
    for (int idx = tid; idx < MI * MI; idx += 256) {
      const int r = idx / MI, c = idx - (idx / MI) * MI;
      u1fOut[(long)img * MI * MI + idx] = A[r][c];
    }
  }

  // phi-fold MI -> 16 (256 threads = 256 output coords)
  {
    constexpr int K2 = MI / 16;
    const float sc2 = 1.f / (float)(MI * MI);
    const int ro = tid >> 4, co = tid & 15;
    float re = 0.f, im = 0.f;
    for (int qr = 0; qr < K2; qr++) {
      const int a_ = ro + qr * 16;
      for (int qc = 0; qc < K2; qc++) {
        const int b_ = co + qc * 16;
        const float2 v = A[a_][b_];
        const float fv = phi[a_ * MI + b_];
        re = fmaf(v.x, fv, re);
        im = fmaf(v.y, fv, im);
      }
    }
    FA[ro][co] = make_float2(re * sc2, im * sc2);
  }
  __syncthreads();

  fft2d<16>(FA, FB, W16, 1.f);  // inverse 16x16 (scale already applied)

  const long bidx = img / chDiv;
  const int ch = chBase + (img % chDiv);
  S[((long)bidx * 417 + ch) * 256 + tid] = FA[tid >> 4][tid & 15].x;
}

// s0 fused: phi-fold(XF, 256->16) + ifft16, one block per image.
__global__ __launch_bounds__(256) void s0_kernel(const float2* __restrict__ XF,
                                                 const float* __restrict__ phi0,
                                                 float* __restrict__ S) {
  __shared__ float2 FA[16][17];
  __shared__ float2 FB[16][17];
  __shared__ float2 W16[8];
  const int tid = threadIdx.x;
  const int img = blockIdx.x;
  if (tid < 8) W16[tid] = make_float2(cosf(0.39269908169872415481f * (float)tid),
                                      sinf(0.39269908169872415481f * (float)tid));
  const int r = tid >> 4, c = tid & 15;
  const float2* sp = XF + (long)img * 65536;
  float re = 0.f, im = 0.f;
  for (int qr = 0; qr < 16; qr++) {
    const int R_ = r + qr * 16;
    for (int qc = 0; qc < 16; qc++) {
      const long pos = (long)R_ * 256 + (c + qc * 16);
      const float2 v = sp[pos];
      const float f = phi0[pos];
      re = fmaf(v.x, f, re);
      im = fmaf(v.y, f, im);
    }
  }
  FA[r][c] = make_float2(re / 65536.f, im / 65536.f);
  __syncthreads();
  fft2d<16>(FA, FB, W16, 1.f);
  S[((long)img * 417 + 0) * 256 + tid] = FA[r][c].x;
}

// Final 16x16 inverse FFT of a folded spectrum (from the fused folds), write S.
__global__ __launch_bounds__(256) void ifft16_kernel(const float2* __restrict__ spec,
                                                     float* __restrict__ S,
                                                     int chBase, int chDiv) {
  __shared__ float2 FA[16][17];
  __shared__ float2 FB[16][17];
  __shared__ float2 W16[8];
  const int tid = threadIdx.x;
  const int img = blockIdx.x;
  if (tid < 8) W16[tid] = make_float2(cosf(0.39269908169872415481f * (float)tid),
                                      sinf(0.39269908169872415481f * (float)tid));
  FA[tid >> 4][tid & 15] = spec[(long)img * 256 + tid];
  __syncthreads();
  fft2d<16>(FA, FB, W16, 1.f);
  const long bidx = img / chDiv;
  const int ch = chBase + (img % chDiv);
  S[((long)bidx * 417 + ch) * 256 + tid] = FA[tid >> 4][tid & 15].x;
}

// ---------------------------------------------------------------------------
// Filter banks (computed on device in f64, mirroring numpy exactly)
// PSI banks: (r,js) = (0,0)(0,1)(0,2)(0,3)(1,1)(1,2)(2,1), 8 orientations each
// ---------------------------------------------------------------------------
__device__ const long PSI_CUM[7] = {524288, 1048576, 1572864, 2097152, 2228224, 2359296, 2392064};
__device__ const int  PSI_MM[7]  = {256, 256, 256, 256, 128, 128, 64};
__device__ const int  PSI_JS[7]  = {0, 1, 2, 3, 1, 2, 1};

__device__ __forceinline__ double dfreq(int i, int m) {
  return (double)((i < (m >> 1)) ? i : i - m) / (double)m;
}

__global__ __launch_bounds__(256) void build_psi_kernel(float* psi, int* fmax) {
  const long i = (long)blockIdx.x * 256 + threadIdx.x;
  int bank = 0;
  while (i >= PSI_CUM[bank]) bank++;
  const long base = bank ? PSI_CUM[bank - 1] : 0;
  const long rem = i - base;
  const int m = PSI_MM[bank], js = PSI_JS[bank];
  const long mm2 = (long)m * m;
  const int l = (int)(rem / mm2);
  const long pos = rem - (long)l * mm2;
  const int r = (int)(pos / m), c = (int)(pos - (long)r * m);
  const double sigma = 0.8 * (double)(1 << js);
  const double xi = (3.0 * PI_D / 4.0) / (double)(1 << js);
  const double th = (double)l * PI_D / 8.0;
  const double kx = 2.0 * PI_D * dfreq(r, m);
  const double ky = 2.0 * PI_D * dfreq(c, m);
  const double ct = cos(th), st = sin(th);
  const double w1 = kx * ct + ky * st;
  const double w2 = -kx * st + ky * ct;
  const double s2 = sigma * sigma;
  const double aa  = exp(-0.5 * s2 * ((w1 - xi) * (w1 - xi) + 0.25 * w2 * w2));
  const double env = exp(-0.5 * s2 * (w1 * w1 + 0.25 * w2 * w2));
  const double beta = exp(-0.5 * s2 * xi * xi);
  const double f = aa - beta * env;
  psi[i] = (float)f;

  float v = fmaxf((float)f, 0.f);
  #pragma unroll
  for (int off = 32; off > 0; off >>= 1)
    v = fmaxf(v, __shfl_down(v, off, 64));
  __shared__ float wmax[4];
  const int lane = threadIdx.x & 63, wid = threadIdx.x >> 6;
  if (lane == 0) wmax[wid] = v;
  __syncthreads();
  if (threadIdx.x == 0) {
    const float mv = fmaxf(fmaxf(wmax[0], wmax[1]), fmaxf(wmax[2], wmax[3]));
    atomicMax(&fmax[bank * 8 + l], __float_as_int(mv));
  }
}

__global__ void norm_psi_kernel(float* psi, const int* fmax) {
  const long i = (long)blockIdx.x * 256 + threadIdx.x;
  if (i >= 2392064L) return;
  int bank = 0;
  while (i >= PSI_CUM[bank]) bank++;
  const long base = bank ? PSI_CUM[bank - 1] : 0;
  const long rem = i - base;
  const int m = PSI_MM[bank];
  const int l = (int)(rem / ((long)m * m));
  const float mx = fmaxf(__int_as_float(fmax[bank * 8 + l]), 1e-12f);
  psi[i] = psi[i] / mx;
}

__global__ void build_phi_kernel(float* phi) {
  const long i = (long)blockIdx.x * 256 + threadIdx.x;
  if (i >= 87040L) return;
  int rr; long base;
  if (i < 65536) { rr = 0; base = 0; }
  else if (i < 81920) { rr = 1; base = 65536; }
  else if (i < 86016) { rr = 2; base = 81920; }
  else { rr = 3; base = 86016; }
  const int m = 256 >> rr;
  const double sigma = 0.8 * (double)(1 << (4 - rr));
  const long pos = i - base;
  const int r = (int)(pos / m), c = (int)(pos % m);
  const double kx = 2.0 * PI_D * dfreq(r, m);
  const double ky = 2.0 * PI_D * dfreq(c, m);
  phi[i] = (float)exp(-0.5 * sigma * sigma * (kx * kx + ky * ky));
}

// ---------------------------------------------------------------------------
// MLP
// ---------------------------------------------------------------------------
__global__ __launch_bounds__(256) void mlp1_kernel(const float* __restrict__ S,
                                                   const float* __restrict__ w1,
                                                   float* __restrict__ out1) {
  __shared__ float hs[16][256];
  const int o = blockIdx.x * 256 + threadIdx.x;   // 1024 outputs over 4 blocks
  const int ch = blockIdx.y;                      // 417 k-chunks of 256
  for (int idx = threadIdx.x; idx < 16 * 256; idx += 256) {
    const int b = idx >> 8, kk = idx & 255;
    hs[b][kk] = S[((long)b * 417 + ch) * 256 + kk];
  }
  __syncthreads();
  float acc[16];
  #pragma unroll
  for (int b = 0; b < 16; b++) acc[b] = 0.f;
  const float* wp = w1 + (long)ch * 256 * 1024 + o;
  for (int kk = 0; kk < 256; kk++) {
    const float w = wp[(long)kk * 1024];
    #pragma unroll
    for (int b = 0; b < 16; b++) acc[b] = fmaf(hs[b][kk], w, acc[b]);
  }
  #pragma unroll
  for (int b = 0; b < 16; b++) atomicAdd(&out1[b * 1024 + o], acc[b]);
}

// mlp2 with layer-1 post (bias+relu+bn) fused into the LDS staging
__global__ __launch_bounds__(256) void mlp2_kernel(const float* __restrict__ out1,
                                                   const float* __restrict__ b1,
                                                   const float* __restrict__ g1, const float* __restrict__ bb1,
                                                   const float* __restrict__ mm1, const float* __restrict__ vv1,
                                                   const float* w2, const float* b2,
                                                   const float* g, const float* bb, const float* mm,
                                                   const float* vv, float* h2) {
  __shared__ float hs[16][256];
  const int o = blockIdx.x * 256 + threadIdx.x;   // 512 outputs over 2 blocks
  float acc[16];
  #pragma unroll
  for (int b = 0; b < 16; b++) acc[b] = 0.f;
  for (int kc = 0; kc < 4; kc++) {
    __syncthreads();
    for (int idx = threadIdx.x; idx < 16 * 256; idx += 256) {
      const int b = idx >> 8, kk = idx & 255;
      const int feat = kc * 256 + kk;
      const float xv = fmaxf(out1[b * 1024 + feat] + b1[feat], 0.f);
      const float rs = (float)(1.0 / sqrt((double)vv1[feat] + 1e-5));
      hs[b][kk] = (xv - mm1[feat]) * rs * g1[feat] + bb1[feat];
    }
    __syncthreads();
    for (int kk = 0; kk < 256; kk++) {
      const float w = w2[(long)(kc * 256 + kk) * 512 + o];
      #pragma unroll
      for (int b = 0; b < 16; b++) acc[b] = fmaf(hs[b][kk], w, acc[b]);
    }
  }
  const float bias = b2[o], gg = g[o], bbv = bb[o], mv = mm[o];
  const float rs = (float)(1.0 / sqrt((double)vv[o] + 1e-5));
  for (int b = 0; b < 16; b++) {
    const float xv = fmaxf(acc[b] + bias, 0.f);
    h2[b * 512 + o] = (xv - mv) * rs * gg + bbv;
  }
}

// mlp3 + mlp4 fused (single block)
__global__ __launch_bounds__(128) void mlp34_kernel(const float* h2, const float* w3, const float* b3,
                                                    const float* g, const float* bb, const float* mm,
                                                    const float* vv, const float* w4, const float* b4,
                                                    float* out) {
  __shared__ float hs[16][256];
  __shared__ float h3s[16][128];
  const int o = threadIdx.x;   // 128 outputs
  float acc[16];
  #pragma unroll
  for (int b = 0; b < 16; b++) acc[b] = 0.f;
  for (int kc = 0; kc < 2; kc++) {
    __syncthreads();
    for (int idx = threadIdx.x; idx < 16 * 256; idx += 128) {
      const int b = idx >> 8, kk = idx & 255;
      hs[b][kk] = h2[b * 512 + kc * 256 + kk];
    }
    __syncthreads();
    for (int kk = 0; kk < 256; kk++) {
      const float w = w3[(kc * 256 + kk) * 128 + o];
      #pragma unroll
      for (int b = 0; b < 16; b++) acc[b] = fmaf(hs[b][kk], w, acc[b]);
    }
  }
  const float bias = b3[o], gg = g[o], bbv = bb[o], mv = mm[o];
  const float rs = (float)(1.0 / sqrt((double)vv[o] + 1e-5));
  for (int b = 0; b < 16; b++) {
    const float xv = fmaxf(acc[b] + bias, 0.f);
    h3s[b][o] = (xv - mv) * rs * gg + bbv;
  }
  __syncthreads();
  if (threadIdx.x < 16) {
    const int b = threadIdx.x;
    double a = 0.0;
    for (int k = 0; k < 128; k++) a += (double)h3s[b][k] * (double)w4[k];
    out[b] = (float)(a + (double)b4[0]);
  }
}

// ---------------------------------------------------------------------------
// Orchestration
// ---------------------------------------------------------------------------
static RftParams rp0() {
  RftParams p;
  memset(&p, 0, sizeof(p));
  p.srcDiv = 1; p.filtMod = 1; p.chDiv = 1;
  p.scale = 1.f; p.sign = -1.f; p.m1 = 0;
  return p;
}

extern "C" void kernel_launch(void* const* d_in, const int* in_sizes, int n_in,
                              void* d_out, int out_size, void* d_ws, size_t ws_size,
                              hipStream_t stream) {
  (void)in_sizes; (void)n_in; (void)out_size; (void)ws_size;
  const float* x    = (const float*)d_in[0];
  const float* w1   = (const float*)d_in[1];
  const float* b1   = (const float*)d_in[2];
  const float* bn1g = (const float*)d_in[3];
  const float* bn1b = (const float*)d_in[4];
  const float* bn1m = (const float*)d_in[5];
  const float* bn1v = (const float*)d_in[6];
  const float* w2   = (const float*)d_in[7];
  const float* b2   = (const float*)d_in[8];
  const float* bn2g = (const float*)d_in[9];
  const float* bn2b = (const float*)d_in[10];
  const float* bn2m = (const float*)d_in[11];
  const float* bn2v = (const float*)d_in[12];
  const float* w3   = (const float*)d_in[13];
  const float* b3   = (const float*)d_in[14];
  const float* bn3g = (const float*)d_in[15];
  const float* bn3b = (const float*)d_in[16];
  const float* bn3m = (const float*)d_in[17];
  const float* bn3v = (const float*)d_in[18];
  const float* w4   = (const float*)d_in[19];
  const float* b4   = (const float*)d_in[20];

  char* ws = (char*)d_ws;
  const size_t MB = 1048576;
  float2* XF   = (float2*)(ws + 0 * MB);     //   8 MiB: fft2(x), 16 x 256^2
  float2* BUF1 = (float2*)(ws + 8 * MB);     //  64 MiB ping (complex)
  float2* BUF2 = (float2*)(ws + 72 * MB);    //  32 MiB (real abs images)
  float2* U1F0 = (float2*)(ws + 104 * MB);   //  64 MiB: u1f at j1=0 (128 x 256^2)
  float2* U1F1 = (float2*)(ws + 168 * MB);   //  16 MiB: u1f at j1=1 (128 x 128^2)
  float2* U1F2 = (float2*)(ws + 184 * MB);   //   4 MiB: u1f at j1=2 (128 x  64^2)
  float*  S    = (float*)(ws + 188 * MB);    //   6.6 MiB: 16 x 417 x 256
  float*  PSI  = (float*)(ws + 195 * MB);    //   9.2 MiB
  float*  PHI  = (float*)(ws + 205 * MB);    //   0.4 MiB
  int*    FMAX = (int*)(ws + 206 * MB);      //   256 B
  float2* SF   = (float2*)(ws + 207 * MB);   //   2.5 MiB: folded 16x16 spectra
  float2* G64  = (float2*)(ws + 210 * MB);   //  32 MiB: prefolded 64^2 images (1024 max)
  float2* G32  = (float2*)(ws + 242 * MB);   //   8 MiB: prefolded 32^2 images (1024 max)
  float*  OUT1 = (float*)(ws + 251 * MB);    //  16 x 1024
  float*  H2   = (float*)(ws + 252 * MB);

  float2* SF0  = SF;                 // j1=0 s1 spectra: 128 imgs
  float2* SF1  = SF + 128 * 256;     // j1=1 s1 spectra: 128 imgs
  float2* SF01 = SF + 256 * 256;     // (0,1) s2 spectra: 1024 imgs

  static const int psioff[7] = {0, 524288, 1048576, 1572864, 2097152, 2228224, 2359296};
  static const int phioff[4] = {0, 65536, 81920, 86016};

  // ---- filters (deterministic, rebuilt every call) ----
  hipMemsetAsync(FMAX, 0, 256, stream);
  hipMemsetAsync(SF, 0, 1280 * 256 * sizeof(float2), stream);
  build_psi_kernel<<<9344, 256, 0, stream>>>(PSI, FMAX);
  norm_psi_kernel<<<9344, 256, 0, stream>>>(PSI, FMAX);
  build_phi_kernel<<<340, 256, 0, stream>>>(PHI);

  // ---- Xf = fft2(x) ----
  { RftParams p = rp0(); p.inMode = IN_REAL; p.srcR = x; p.outMode = OUT_COMPLEX; p.dstC = BUF1; p.sign = -1.f; rft_go(256, 16, p, stream); }
  { RftParams p = rp0(); p.inMode = IN_COMPLEX; p.srcC = BUF1; p.outMode = OUT_COMPLEX; p.dstC = XF; p.sign = -1.f; rft_go(256, 16, p, stream); }

  // ---- s0 (fused fold + ifft16) ----
  s0_kernel<<<16, 256, 0, stream>>>(XF, PHI + phioff[0], S);

  // ---- first order, j1 = 0,1 (m1 = 256,128): 4 rft passes, fold fused in p4 ----
  for (int j1 = 0; j1 < 2; j1++) {
    const int m1 = 256 >> j1;
    const float isc1 = 1.f / (float)(m1 * m1);
    float2* U  = (j1 == 0) ? U1F0 : U1F1;
    float2* SFj = (j1 == 0) ? SF0 : SF1;
    { RftParams p = rp0(); p.inMode = IN_MULFOLD; p.srcC = XF; p.filt = PSI + psioff[j1]; p.m1 = 256; p.srcDiv = 8; p.filtMod = 8; p.scale = 1.f / 65536.f; p.sign = 1.f; p.outMode = OUT_COMPLEX; p.dstC = BUF1; rft_go(m1, 128, p, stream); }
    { RftParams p = rp0(); p.inMode = IN_COMPLEX; p.srcC = BUF1; p.sign = 1.f; p.outMode = OUT_ABS; p.dstR = (float*)BUF2; rft_go(m1, 128, p, stream); }
    { RftParams p = rp0(); p.inMode = IN_REAL; p.srcR = (const float*)BUF2; p.sign = -1.f; p.outMode = OUT_COMPLEX; p.dstC = BUF1; rft_go(m1, 128, p, stream); }
    { RftParams p = rp0(); p.inMode = IN_COMPLEX; p.srcC = BUF1; p.sign = -1.f; p.outMode = OUT_COMPLEX_FOLD; p.dstC = U;
      p.foldDst = SFj; p.foldPhi = PHI + phioff[j1]; p.foldScale = isc1; rft_go(m1, 128, p, stream); }
    ifft16_kernel<<<128, 256, 0, stream>>>(SFj, S, 1 + 8 * j1, 8);
  }

  // ---- first order, j1 = 2,3: fold8 prefold + prefolded chain ----
  fold8_kernel<256, 64><<<16 * 16, 256, 0, stream>>>(XF, PSI + psioff[2], G64, 1.f / 65536.f);
  chain_kernel<64, 64><<<128, 256, 0, stream>>>(G64, nullptr, PHI + phioff[2], U1F2, S, 17, 8);
  fold8_kernel<256, 32><<<16 * 4, 256, 0, stream>>>(XF, PSI + psioff[3], G32, 1.f / 65536.f);
  chain_kernel<32, 32><<<128, 256, 0, stream>>>(G32, nullptr, PHI + phioff[3], nullptr, S, 25, 8);

  // ---- second order (0,1), m2 = 128: 4 rft passes per chunk, u2f never written ----
  for (int cc = 0; cc < 2; cc++) {
    const int b0 = cc * 8;
    const float2* u1fsrc = U1F0 + (long)b0 * 8 * 65536;
    { RftParams p = rp0(); p.inMode = IN_MULFOLD; p.srcC = u1fsrc; p.filt = PSI + psioff[1]; p.m1 = 256; p.srcDiv = 8; p.filtMod = 8; p.scale = 1.f / 65536.f; p.sign = 1.f; p.outMode = OUT_COMPLEX; p.dstC = BUF1; rft_go(128, 512, p, stream); }
    { RftParams p = rp0(); p.inMode = IN_COMPLEX; p.srcC = BUF1; p.sign = 1.f; p.outMode = OUT_ABS; p.dstR = (float*)BUF2; rft_go(128, 512, p, stream); }
    { RftParams p = rp0(); p.inMode = IN_REAL; p.srcR = (const float*)BUF2; p.sign = -1.f; p.outMode = OUT_COMPLEX; p.dstC = BUF1; rft_go(128, 512, p, stream); }
    { RftParams p = rp0(); p.inMode = IN_COMPLEX; p.srcC = BUF1; p.sign = -1.f; p.outMode = OUT_FOLD;
      p.foldDst = SF01 + (long)b0 * 64 * 256; p.foldPhi = PHI + phioff[1]; p.foldScale = 1.f / 16384.f; rft_go(128, 512, p, stream); }
  }
  ifft16_kernel<<<1024, 256, 0, stream>>>(SF01, S, 33, 64);

  // ---- second order, m2 <= 64: fold8 prefold + prefolded chains ----
  fold8_kernel<256, 64><<<128 * 16, 256, 0, stream>>>(U1F0, PSI + psioff[2], G64, 1.f / 65536.f);
  chain_kernel<64, 64><<<1024, 256, 0, stream>>>(G64, nullptr, PHI + phioff[2], nullptr, S,  97, 64);
  fold8_kernel<256, 32><<<128 * 4, 256, 0, stream>>>(U1F0, PSI + psioff[3], G32, 1.f / 65536.f);
  chain_kernel<32, 32><<<1024, 256, 0, stream>>>(G32, nullptr, PHI + phioff[3], nullptr, S, 161, 64);
  fold8_kernel<128, 64><<<128 * 16, 256, 0, stream>>>(U1F1, PSI + psioff[4], G64, 1.f / 16384.f);
  chain_kernel<64, 64><<<1024, 256, 0, stream>>>(G64, nullptr, PHI + phioff[2], nullptr, S, 225, 64);
  fold8_kernel<128, 32><<<128 * 4, 256, 0, stream>>>(U1F1, PSI + psioff[5], G32, 1.f / 16384.f);
  chain_kernel<32, 32><<<1024, 256, 0, stream>>>(G32, nullptr, PHI + phioff[3], nullptr, S, 289, 64);
  fold8_kernel<64, 32><<<128 * 4, 256, 0, stream>>>(U1F2, PSI + psioff[6], G32, 1.f / 4096.f);
  chain_kernel<32, 32><<<1024, 256, 0, stream>>>(G32, nullptr, PHI + phioff[3], nullptr, S, 353, 64);

  // ---- MLP ----
  hipMemsetAsync(OUT1, 0, 16 * 1024 * 4, stream);
  mlp1_kernel<<<dim3(4, 417), 256, 0, stream>>>(S, w1, OUT1);
  mlp2_kernel<<<2, 256, 0, stream>>>(OUT1, b1, bn1g, bn1b, bn1m, bn1v,
                                     w2, b2, bn2g, bn2b, bn2m, bn2v, H2);
  mlp34_kernel<<<1, 128, 0, stream>>>(H2, w3, b3, bn3g, bn3b, bn3m, bn3v, w4, b4, (float*)d_out);
}